// Round 2
// baseline (1162.469 us; speedup 1.0000x reference)
//
#include <hip/hip_runtime.h>

#define B_   32
#define C_   128
#define L_   4096
#define FL_  9
#define DIM_ 512
#define BCL  ((size_t)B_ * C_ * L_)

typedef __attribute__((ext_vector_type(8))) short short8;
typedef __attribute__((ext_vector_type(4))) float f32x4;

__device__ __forceinline__ float gelu_f(float x) {
    return 0.5f * x * (1.0f + erff(x * 0.70710678118654752440f));
}
__device__ __forceinline__ float sigm_f(float x) {
    return 1.0f / (1.0f + expf(-x));
}
__device__ __forceinline__ unsigned short bf16_rne(float x) {
    unsigned int u = __float_as_uint(x);
    u += 0x7fffu + ((u >> 16) & 1u);
    return (unsigned short)(u >> 16);
}
__device__ __forceinline__ float bf16_to_f(unsigned short h) {
    return __uint_as_float(((unsigned int)h) << 16);
}

// ---------------- one-time weight split into bf16 hi/lo, K-major ----------------
__global__ __launch_bounds__(256) void prep_weights(
    const float* __restrict__ gw, const float* __restrict__ a1w, const float* __restrict__ a2w,
    unsigned short* __restrict__ wgh, unsigned short* __restrict__ wgl,
    unsigned short* __restrict__ a1h, unsigned short* __restrict__ a1l,
    unsigned short* __restrict__ a2h, unsigned short* __restrict__ a2l) {
    int i = blockIdx.x * 256 + threadIdx.x;
    float v; unsigned short* ph; unsigned short* pl; int idx;
    if (i < 147456) {
        int lev = i / 49152, r = i % 49152;
        int co = r / 384, k = r % 384, kp = k >> 7, ci = k & 127;
        v = gw[(((size_t)lev * C_ + co) * C_ + ci) * 3 + kp];
        ph = wgh; pl = wgl; idx = i;
    } else if (i < 147456 + 8192) {
        idx = i - 147456;
        v = a1w[idx];
        ph = a1h; pl = a1l;
    } else if (i < 147456 + 16384) {
        idx = i - 147456 - 8192;
        v = a2w[idx];
        ph = a2h; pl = a2l;
    } else return;
    unsigned short h = bf16_rne(v);
    unsigned short l = bf16_rne(v - bf16_to_f(h));
    ph[idx] = h; pl[idx] = l;
}

__device__ __forceinline__ float block_sum_256(float v, float* red) {
    #pragma unroll
    for (int off = 32; off > 0; off >>= 1) v += __shfl_down(v, off);
    const int wv = threadIdx.x >> 6, ln = threadIdx.x & 63;
    if (ln == 0) red[wv] = v;
    __syncthreads();
    return red[0] + red[1] + red[2] + red[3];
}

// ---------------- mean over L (level 0 feat), float4 ----------------
__global__ __launch_bounds__(256) void mean_kernel(const float* __restrict__ in,
                                                   float* __restrict__ feat_sum) {
    __shared__ float red[4];
    const int bc = blockIdx.x, t = threadIdx.x;
    const float4* p = (const float4*)(in + (size_t)bc * L_);
    float v = 0.f;
    #pragma unroll
    for (int it = 0; it < L_ / 1024; it++) {
        float4 x = p[t + 256 * it];
        v += x.x + x.y + x.z + x.w;
    }
    float tot = block_sum_256(v, red);
    if (t == 0) feat_sum[bc] = tot;
}

// ---------------- MLP layer ----------------
template <int K, int ACT>
__global__ __launch_bounds__(256) void mlp_layer(
    const float* __restrict__ X, const float* __restrict__ W,
    const float* __restrict__ bias, float* __restrict__ Y,
    int N, float xscale) {
    constexpr int PL = K / 64;
    const int w = threadIdx.x >> 6, ln = threadIdx.x & 63;
    const int s = blockIdx.y;
    const int o0 = blockIdx.x * 16 + w * 4;
    float xv[PL];
    const float* xr = X + (size_t)s * K + ln * PL;
    if constexpr (PL == 2) {
        float2 v = *(const float2*)xr;
        xv[0] = v.x * xscale; xv[1] = v.y * xscale;
    } else {
        #pragma unroll
        for (int i = 0; i < PL / 4; i++) {
            float4 v = *(const float4*)(xr + 4 * i);
            xv[4*i] = v.x * xscale; xv[4*i+1] = v.y * xscale;
            xv[4*i+2] = v.z * xscale; xv[4*i+3] = v.w * xscale;
        }
    }
    #pragma unroll
    for (int r = 0; r < 4; r++) {
        int o = o0 + r;
        if (o < N) {
            const float* wr = W + (size_t)o * K + ln * PL;
            float acc = 0.f;
            if constexpr (PL == 2) {
                float2 v = *(const float2*)wr;
                acc = v.x * xv[0] + v.y * xv[1];
            } else {
                #pragma unroll
                for (int i = 0; i < PL / 4; i++) {
                    float4 v = *(const float4*)(wr + 4 * i);
                    acc += v.x * xv[4*i] + v.y * xv[4*i+1] + v.z * xv[4*i+2] + v.w * xv[4*i+3];
                }
            }
            #pragma unroll
            for (int off = 32; off > 0; off >>= 1) acc += __shfl_xor(acc, off);
            if (ln == 0) {
                acc += bias[o];
                Y[(size_t)s * N + o] = ACT ? gelu_f(acc) : acc;
            }
        }
    }
}

// ---------------- MLP final layer ----------------
__global__ __launch_bounds__(256) void mlp_l3(
    const float* __restrict__ X, const float* __restrict__ W, const float* __restrict__ bias,
    float* __restrict__ lo_out, float* __restrict__ hi_out) {
    constexpr int K = 2 * DIM_, PL = K / 64;
    const int w = threadIdx.x >> 6, ln = threadIdx.x & 63;
    const int s = blockIdx.y;
    const int o0 = blockIdx.x * 16 + w * 4;
    float xv[PL];
    const float* xr = X + (size_t)s * K + ln * PL;
    #pragma unroll
    for (int i = 0; i < PL / 4; i++) {
        float4 v = *(const float4*)(xr + 4 * i);
        xv[4*i] = v.x; xv[4*i+1] = v.y; xv[4*i+2] = v.z; xv[4*i+3] = v.w;
    }
    #pragma unroll
    for (int r = 0; r < 4; r++) {
        int o = o0 + r;
        if (o < 2 * FL_) {
            const float* wr = W + (size_t)o * K + ln * PL;
            float acc = 0.f;
            #pragma unroll
            for (int i = 0; i < PL / 4; i++) {
                float4 v = *(const float4*)(wr + 4 * i);
                acc += v.x * xv[4*i] + v.y * xv[4*i+1] + v.z * xv[4*i+2] + v.w * xv[4*i+3];
            }
            #pragma unroll
            for (int off = 32; off > 0; off >>= 1) acc += __shfl_xor(acc, off);
            if (ln == 0) {
                acc += bias[o];
                if (o < FL_) lo_out[s * FL_ + o] = acc;
                else         hi_out[s * FL_ + (o - FL_)] = acc;
            }
        }
    }
}

// ---------------- per-sample depthwise 9-tap conv (edge pad) + optional halo sidecar ----
__global__ __launch_bounds__(256) void dwconv_kernel(
    const float* __restrict__ in, const float* __restrict__ lo_f, const float* __restrict__ hi_f,
    float* __restrict__ out_lo, float* __restrict__ out_hi, float* __restrict__ feat_next,
    float* __restrict__ Hout) {
    __shared__ float s[1032];
    __shared__ float red[4];
    const int t = threadIdx.x;
    const int l0 = blockIdx.x * 1024;
    const int c = blockIdx.y, b = blockIdx.z;
    const size_t base = ((size_t)b * C_ + c) * L_;
    *(float4*)&s[4 + 4 * t] = *(const float4*)&in[base + l0 + 4 * t];
    if (t < 4) {
        int gl = l0 - 4 + t;
        s[t] = in[base + max(gl, 0)];
    } else if (t < 8) {
        int i = t - 4;
        s[1028 + i] = in[base + min(l0 + 1024 + i, L_ - 1)];
    }
    float lo[FL_], hi[FL_];
    #pragma unroll
    for (int k = 0; k < FL_; k++) { lo[k] = lo_f[b * FL_ + k]; hi[k] = hi_f[b * FL_ + k]; }
    __syncthreads();
    float oL[4] = {0, 0, 0, 0}, oH[4] = {0, 0, 0, 0};
    #pragma unroll
    for (int k = 0; k < FL_; k++) {
        #pragma unroll
        for (int r = 0; r < 4; r++) {
            float v = s[4 * t + r + k];
            oL[r] += lo[k] * v; oH[r] += hi[k] * v;
        }
    }
    *(float4*)&out_lo[base + l0 + 4 * t] = *(float4*)oL;
    *(float4*)&out_hi[base + l0 + 4 * t] = *(float4*)oH;
    if (Hout) {
        // duplicate det values at tile-boundary columns for the fused recon halo
        int p0 = l0 + 4 * t;
        if ((p0 & 63) == 0)  Hout[(((size_t)b * C_ + c) * 64 + (p0 >> 6)) * 2 + 0] = oH[0];
        int p3 = p0 + 3;
        if ((p3 & 63) == 63) Hout[(((size_t)b * C_ + c) * 64 + (p3 >> 6)) * 2 + 1] = oH[3];
    }
    if (feat_next) {
        float tot = block_sum_256(oL[0] + oL[1] + oL[2] + oL[3], red);
        if (t == 0) atomicAdd(&feat_next[b * C_ + c], tot);
    }
}

// ---------------- ortho + energy scalars ----------------
__global__ void ortho_kernel(const float* __restrict__ lo2, float* __restrict__ scal) {
    const int t = threadIdx.x;
    float smooth = 0.f, sabs2 = 0.f, amp = 0.f;
    if (t < B_) {
        const float* lo = lo2 + t * FL_;
        float ss = 0.f, sa = 0.f, sm = 0.f, prev = 0.f;
        #pragma unroll
        for (int k = 0; k < FL_; k++) {
            float v = lo[k];
            sm += fabsf(v - prev); prev = v;
            ss += v * v; sa += fabsf(v);
        }
        sm += fabsf(prev);
        float den = sqrtf(ss) + 1e-8f;
        float san = sa / den;
        sabs2 = san * san;
        amp = fabsf(ss / (den * den) - 1.0f);
        smooth = sm;
    }
    #pragma unroll
    for (int off = 32; off > 0; off >>= 1) {
        smooth += __shfl_down(smooth, off);
        sabs2  += __shfl_down(sabs2, off);
        amp    += __shfl_down(amp, off);
    }
    if (t == 0) {
        float lo_smooth = smooth / (float)(B_ * 10);
        float shift = 3.0f * (sabs2 / (float)B_) / 81.0f;
        scal[0] = 0.01f * (shift + amp / (float)B_) + 0.1f * lo_smooth;
        scal[1] = 0.0f;
    }
}

// ---------------- fused 3-stage reconstruction (split-bf16 MFMA) ----------------
// Staged rows li=0..81 <-> global pos g = l0-5+li. Out rows lp = 16*tn+ln+1 (1..80),
// out pos gl = l0 + 16*tn+ln - 4. Core = off in [4,68). LDS = 57.4 KB -> 2 blocks/CU.
#define LT   64
#define XR   82
#define NT   5
#define SX   136
#define SA   40
__global__ __launch_bounds__(256, 2) void recon_fused(
    const float* __restrict__ cur_in, const float* __restrict__ det2,
    float* det1, const float* __restrict__ det1H, float* det0,
    float* __restrict__ cur_out,
    const unsigned short* __restrict__ wgh, const unsigned short* __restrict__ wgl,
    const float* __restrict__ gb,
    const unsigned short* __restrict__ a1h, const unsigned short* __restrict__ a1l,
    const float* __restrict__ b1,
    const unsigned short* __restrict__ a2h, const unsigned short* __restrict__ a2l,
    const float* __restrict__ b2) {
    __shared__ __attribute__((aligned(16))) unsigned short Xh[XR * SX];
    __shared__ __attribute__((aligned(16))) unsigned short Xl[XR * SX];
    __shared__ __attribute__((aligned(16))) unsigned short aTh[80 * SA];
    __shared__ __attribute__((aligned(16))) unsigned short aTl[80 * SA];

    const int t = threadIdx.x, b = blockIdx.y, T = blockIdx.x;
    const int l0 = T * LT;
    const float* curb = cur_in + (size_t)b * (C_ * L_);

    // ---- one-time staging of cur with +/-5 halo ----
    for (int u = t; u < 64 * XR; u += 256) {
        int cp = u / XR, li = u - cp * XR;
        int gl = l0 - 5 + li;
        float v0 = 0.f, v1 = 0.f;
        if (gl >= 0 && gl < L_) {
            v0 = curb[(size_t)(2 * cp) * L_ + gl];
            v1 = curb[(size_t)(2 * cp + 1) * L_ + gl];
        }
        unsigned short h0 = bf16_rne(v0), h1 = bf16_rne(v1);
        unsigned short e0 = bf16_rne(v0 - bf16_to_f(h0)), e1 = bf16_rne(v1 - bf16_to_f(h1));
        ((unsigned int*)Xh)[li * (SX / 2) + cp] = (unsigned int)h0 | ((unsigned int)h1 << 16);
        ((unsigned int*)Xl)[li * (SX / 2) + cp] = (unsigned int)e0 | ((unsigned int)e1 << 16);
    }
    __syncthreads();

    const int w = t >> 6, ln = t & 15, q = (t >> 4) & 3;

    // ---- cur carried in registers across stages ----
    float cur[2][NT][4];
    #pragma unroll
    for (int tm = 0; tm < 2; tm++)
        #pragma unroll
        for (int tn = 0; tn < NT; tn++) {
            int cp0 = 16 * w + 8 * tm + 2 * q;
            int lp = 16 * tn + ln + 1;
            #pragma unroll
            for (int pr = 0; pr < 2; pr++) {
                unsigned int uh = ((unsigned int*)Xh)[lp * (SX / 2) + cp0 + pr];
                unsigned int ul = ((unsigned int*)Xl)[lp * (SX / 2) + cp0 + pr];
                cur[tm][tn][2 * pr]     = bf16_to_f((unsigned short)(uh & 0xffff)) +
                                          bf16_to_f((unsigned short)(ul & 0xffff));
                cur[tm][tn][2 * pr + 1] = bf16_to_f((unsigned short)(uh >> 16)) +
                                          bf16_to_f((unsigned short)(ul >> 16));
            }
        }

    for (int s = 0; s < 3; s++) {
        const int lev = 2 - s;
        const unsigned short* wh = wgh + lev * 49152;
        const unsigned short* wl = wgl + lev * 49152;
        const float* gbb = gb + lev * C_;

        // ---- det prefetch (race-free: yh2 full, yh1 core+sidecar halo, yh0 core) ----
        float dv[2][NT][4];
        #pragma unroll
        for (int tm = 0; tm < 2; tm++)
            #pragma unroll
            for (int tn = 0; tn < NT; tn++)
                #pragma unroll
                for (int r = 0; r < 4; r++) {
                    int co = 32 * w + 16 * tm + 4 * q + r;
                    int off = 16 * tn + ln;
                    int gl = l0 + off - 4;
                    float d = 0.f;
                    if (s == 0) {
                        if (gl >= 0 && gl < L_) d = det2[((size_t)b * C_ + co) * L_ + gl];
                    } else if (s == 1) {
                        if (off >= 4 && off < 68) d = det1[((size_t)b * C_ + co) * L_ + gl];
                        else if (off == 3 && T > 0)   d = det1H[(((size_t)b * C_ + co) * 64 + (T - 1)) * 2 + 1];
                        else if (off == 68 && T < 63) d = det1H[(((size_t)b * C_ + co) * 64 + (T + 1)) * 2 + 0];
                    } else {
                        if (off >= 4 && off < 68) d = det0[((size_t)b * C_ + co) * L_ + gl];
                    }
                    dv[tm][tn][r] = d;
                }

        // ---- gate conv MFMA ----
        f32x4 acc[2][NT];
        #pragma unroll
        for (int tm = 0; tm < 2; tm++)
            #pragma unroll
            for (int tn = 0; tn < NT; tn++) acc[tm][tn] = (f32x4){0.f, 0.f, 0.f, 0.f};

        #pragma unroll 2
        for (int kk = 0; kk < 12; kk++) {
            const int kp = kk >> 2, ci0 = (kk & 3) * 32;
            short8 ah[2], al[2];
            #pragma unroll
            for (int tm = 0; tm < 2; tm++) {
                int row = 32 * w + 16 * tm + ln;
                ah[tm] = *(const short8*)&wh[row * 384 + kk * 32 + q * 8];
                al[tm] = *(const short8*)&wl[row * 384 + kk * 32 + q * 8];
            }
            #pragma unroll
            for (int tn = 0; tn < NT; tn++) {
                int lrow = 16 * tn + ln + kp;
                const short8 bh = *(const short8*)&Xh[lrow * SX + ci0 + q * 8];
                const short8 bl = *(const short8*)&Xl[lrow * SX + ci0 + q * 8];
                #pragma unroll
                for (int tm = 0; tm < 2; tm++) {
                    acc[tm][tn] = __builtin_amdgcn_mfma_f32_16x16x32_bf16(ah[tm], bh, acc[tm][tn], 0, 0, 0);
                    acc[tm][tn] = __builtin_amdgcn_mfma_f32_16x16x32_bf16(ah[tm], bl, acc[tm][tn], 0, 0, 0);
                    acc[tm][tn] = __builtin_amdgcn_mfma_f32_16x16x32_bf16(al[tm], bh, acc[tm][tn], 0, 0, 0);
                }
            }
        }

        // ---- attn (stages 1,2 = levels 1,0) ----
        if (s >= 1) {
            const int ao = (s == 1) ? 4096 : 0;
            const unsigned short* A1h = a1h + ao; const unsigned short* A1l = a1l + ao;
            const float* B1 = b1 + ((s == 1) ? 32 : 0);
            const unsigned short* A2h = a2h + ao; const unsigned short* A2l = a2l + ao;
            const float* B2 = b2 + ((s == 1) ? C_ : 0);

            // conv1 C->32: 10 (tile, ch-half) units over 4 waves
            for (int u2 = w; u2 < 2 * NT; u2 += 4) {
                int tile = u2 >> 1, ch = u2 & 1;
                f32x4 a1c = (f32x4){0.f, 0.f, 0.f, 0.f};
                #pragma unroll
                for (int kc = 0; kc < 4; kc++) {
                    int ci0 = kc * 32;
                    int lrow = 16 * tile + ln + 1;
                    const short8 bh = *(const short8*)&Xh[lrow * SX + ci0 + q * 8];
                    const short8 bl = *(const short8*)&Xl[lrow * SX + ci0 + q * 8];
                    int row = 16 * ch + ln;
                    short8 fh = *(const short8*)&A1h[row * 128 + ci0 + q * 8];
                    short8 fl = *(const short8*)&A1l[row * 128 + ci0 + q * 8];
                    a1c = __builtin_amdgcn_mfma_f32_16x16x32_bf16(fh, bh, a1c, 0, 0, 0);
                    a1c = __builtin_amdgcn_mfma_f32_16x16x32_bf16(fh, bl, a1c, 0, 0, 0);
                    a1c = __builtin_amdgcn_mfma_f32_16x16x32_bf16(fl, bh, a1c, 0, 0, 0);
                }
                #pragma unroll
                for (int r = 0; r < 4; r++) {
                    int c32 = 16 * ch + 4 * q + r;
                    int lcol = 16 * tile + ln;
                    float v = gelu_f(a1c[r] + B1[c32]);
                    unsigned short h = bf16_rne(v);
                    aTh[lcol * SA + c32] = h;
                    aTl[lcol * SA + c32] = bf16_rne(v - bf16_to_f(h));
                }
            }
            __syncthreads();

            // conv2 32->C, applied per tn to keep register pressure low
            short8 fh2[2], fl2[2];
            #pragma unroll
            for (int tm = 0; tm < 2; tm++) {
                int row = 32 * w + 16 * tm + ln;
                fh2[tm] = *(const short8*)&A2h[row * 32 + q * 8];
                fl2[tm] = *(const short8*)&A2l[row * 32 + q * 8];
            }
            #pragma unroll
            for (int tn = 0; tn < NT; tn++) {
                int lrow = 16 * tn + ln;
                const short8 bh = *(const short8*)&aTh[lrow * SA + q * 8];
                const short8 bl = *(const short8*)&aTl[lrow * SA + q * 8];
                f32x4 c2[2];
                c2[0] = (f32x4){0.f, 0.f, 0.f, 0.f};
                c2[1] = (f32x4){0.f, 0.f, 0.f, 0.f};
                #pragma unroll
                for (int tm = 0; tm < 2; tm++) {
                    c2[tm] = __builtin_amdgcn_mfma_f32_16x16x32_bf16(fh2[tm], bh, c2[tm], 0, 0, 0);
                    c2[tm] = __builtin_amdgcn_mfma_f32_16x16x32_bf16(fh2[tm], bl, c2[tm], 0, 0, 0);
                    c2[tm] = __builtin_amdgcn_mfma_f32_16x16x32_bf16(fl2[tm], bh, c2[tm], 0, 0, 0);
                }
                #pragma unroll
                for (int tm = 0; tm < 2; tm++)
                    #pragma unroll
                    for (int r = 0; r < 4; r++) {
                        int co = 32 * w + 16 * tm + 4 * q + r;
                        float at = sigm_f(c2[tm][r] + B2[co]);
                        dv[tm][tn][r] = dv[tm][tn][r] * (1.f + at);
                    }
            }

            // store updated det (core only — race-free ownership)
            float* dd = (s == 1) ? det1 : det0;
            #pragma unroll
            for (int tm = 0; tm < 2; tm++)
                #pragma unroll
                for (int tn = 0; tn < NT; tn++) {
                    int off = 16 * tn + ln;
                    if (off >= 4 && off < 68) {
                        int gl = l0 + off - 4;
                        #pragma unroll
                        for (int r = 0; r < 4; r++) {
                            int co = 32 * w + 16 * tm + 4 * q + r;
                            dd[((size_t)b * C_ + co) * L_ + gl] = dv[tm][tn][r];
                        }
                    }
                }
        }

        // ---- gate update: cur += sigmoid(conv + b) * det ----
        #pragma unroll
        for (int tm = 0; tm < 2; tm++)
            #pragma unroll
            for (int tn = 0; tn < NT; tn++)
                #pragma unroll
                for (int r = 0; r < 4; r++) {
                    int co = 32 * w + 16 * tm + 4 * q + r;
                    float g = sigm_f(acc[tm][tn][r] + gbb[co]);
                    cur[tm][tn][r] += g * dv[tm][tn][r];
                }

        if (s < 2) {
            __syncthreads();   // all waves done reading X for this stage
            // restage new cur into X rows 1..80 (bf16 split, packed channel pairs)
            #pragma unroll
            for (int tm = 0; tm < 2; tm++)
                #pragma unroll
                for (int tn = 0; tn < NT; tn++) {
                    int lp = 16 * tn + ln + 1;
                    int cp0 = 16 * w + 8 * tm + 2 * q;
                    #pragma unroll
                    for (int pr = 0; pr < 2; pr++) {
                        float v0 = cur[tm][tn][2 * pr], v1 = cur[tm][tn][2 * pr + 1];
                        unsigned short h0 = bf16_rne(v0), h1 = bf16_rne(v1);
                        unsigned short e0 = bf16_rne(v0 - bf16_to_f(h0));
                        unsigned short e1 = bf16_rne(v1 - bf16_to_f(h1));
                        ((unsigned int*)Xh)[lp * (SX / 2) + cp0 + pr] = (unsigned int)h0 | ((unsigned int)h1 << 16);
                        ((unsigned int*)Xl)[lp * (SX / 2) + cp0 + pr] = (unsigned int)e0 | ((unsigned int)e1 << 16);
                    }
                }
            __syncthreads();   // X ready for next stage
        } else {
            // final cur store (core only)
            #pragma unroll
            for (int tm = 0; tm < 2; tm++)
                #pragma unroll
                for (int tn = 0; tn < NT; tn++) {
                    int off = 16 * tn + ln;
                    if (off >= 4 && off < 68) {
                        int gl = l0 + off - 4;
                        #pragma unroll
                        for (int r = 0; r < 4; r++) {
                            int co = 32 * w + 16 * tm + 4 * q + r;
                            cur_out[((size_t)b * C_ + co) * L_ + gl] = cur[tm][tn][r];
                        }
                    }
                }
        }
    }
}

static inline void run_mlp(const float* feat, const float* stat_w, const float* stat_b,
                           const float* wg1_w, const float* wg1_b,
                           const float* wg2_w, const float* wg2_b,
                           float* h1_g, float* h2_g, float* lo_out, float* hi_out,
                           hipStream_t stream) {
    mlp_layer<C_, 1><<<dim3(DIM_ / 16, B_), 256, 0, stream>>>(
        feat, stat_w, stat_b, h1_g, DIM_, 1.0f / (float)L_);
    mlp_layer<DIM_, 1><<<dim3(2 * DIM_ / 16, B_), 256, 0, stream>>>(
        h1_g, wg1_w, wg1_b, h2_g, 2 * DIM_, 1.0f);
    mlp_l3<<<dim3(2, B_), 256, 0, stream>>>(h2_g, wg2_w, wg2_b, lo_out, hi_out);
}

extern "C" void kernel_launch(void* const* d_in, const int* in_sizes, int n_in,
                              void* d_out, int out_size, void* d_ws, size_t ws_size,
                              hipStream_t stream) {
    (void)in_sizes; (void)n_in; (void)out_size; (void)ws_size;
    const float* x       = (const float*)d_in[0];
    const float* stat_w  = (const float*)d_in[1];
    const float* stat_b  = (const float*)d_in[2];
    const float* wg1_w   = (const float*)d_in[3];
    const float* wg1_b   = (const float*)d_in[4];
    const float* wg2_w   = (const float*)d_in[5];
    const float* wg2_b   = (const float*)d_in[6];
    const float* gates_w = (const float*)d_in[7];
    const float* gates_b = (const float*)d_in[8];
    const float* a1w     = (const float*)d_in[9];
    const float* a1b     = (const float*)d_in[10];
    const float* a2w     = (const float*)d_in[11];
    const float* a2b     = (const float*)d_in[12];

    float* out = (float*)d_out;
    float* yl  = out;
    float* yh0 = out + BCL;
    float* yh1 = out + 2 * BCL;
    float* yh2 = out + 3 * BCL;
    float* scal = out + 4 * BCL;
    float* lo_all = scal + 2;
    float* hi_all = lo_all + 3 * B_ * FL_;

    float* wsA   = (float*)d_ws;
    float* featA = wsA + BCL;
    float* featB = featA + B_ * C_;
    float* h1_g  = featB + B_ * C_;
    float* h2_g  = h1_g + B_ * DIM_;
    unsigned short* wgh = (unsigned short*)(h2_g + B_ * 2 * DIM_);
    unsigned short* wgl = wgh + 147456;
    unsigned short* a1h = wgl + 147456;
    unsigned short* a1l = a1h + 8192;
    unsigned short* a2h = a1l + 8192;
    unsigned short* a2l = a2h + 8192;
    float* det1H = (float*)(a2l + 8192);   // 32*128*64*2 floats = 2 MB sidecar

    prep_weights<<<dim3((147456 + 16384 + 255) / 256), 256, 0, stream>>>(
        gates_w, a1w, a2w, wgh, wgl, a1h, a1l, a2h, a2l);

    const dim3 cgrid(L_ / 1024, C_, B_);

    // ---- analysis level 0 ----
    mean_kernel<<<dim3(B_ * C_), 256, 0, stream>>>(x, featA);
    run_mlp(featA, stat_w, stat_b, wg1_w, wg1_b, wg2_w, wg2_b, h1_g, h2_g,
            lo_all, hi_all, stream);
    hipMemsetAsync(featB, 0, B_ * C_ * sizeof(float), stream);
    dwconv_kernel<<<cgrid, 256, 0, stream>>>(x, lo_all, hi_all, wsA, yh0, featB, nullptr);
    // ---- analysis level 1 ----
    run_mlp(featB, stat_w, stat_b, wg1_w, wg1_b, wg2_w, wg2_b, h1_g, h2_g,
            lo_all + B_ * FL_, hi_all + B_ * FL_, stream);
    hipMemsetAsync(featA, 0, B_ * C_ * sizeof(float), stream);
    dwconv_kernel<<<cgrid, 256, 0, stream>>>(wsA, lo_all + B_ * FL_, hi_all + B_ * FL_,
                                             yl, yh1, featA, det1H);
    // ---- analysis level 2 ----
    run_mlp(featA, stat_w, stat_b, wg1_w, wg1_b, wg2_w, wg2_b, h1_g, h2_g,
            lo_all + 2 * B_ * FL_, hi_all + 2 * B_ * FL_, stream);
    dwconv_kernel<<<cgrid, 256, 0, stream>>>(yl, lo_all + 2 * B_ * FL_, hi_all + 2 * B_ * FL_,
                                             wsA, yh2, nullptr, nullptr);
    // ---- scalars ----
    ortho_kernel<<<dim3(1), 64, 0, stream>>>(lo_all + 2 * B_ * FL_, scal);
    // ---- fused reconstruction (levels 2 -> 1 -> 0 in one dispatch) ----
    recon_fused<<<dim3(L_ / LT, B_), 256, 0, stream>>>(
        wsA, yh2, yh1, det1H, yh0, yl,
        wgh, wgl, gates_b,
        a1h, a1l, a1b,
        a2h, a2l, a2b);
}

// Round 3
// 760.944 us; speedup vs baseline: 1.5277x; 1.5277x over previous
//
#include <hip/hip_runtime.h>

#define B_   32
#define C_   128
#define L_   4096
#define FL_  9
#define DIM_ 512
#define BCL  ((size_t)B_ * C_ * L_)

typedef __attribute__((ext_vector_type(8))) short short8;
typedef __attribute__((ext_vector_type(4))) float f32x4;

__device__ __forceinline__ float gelu_f(float x) {
    return 0.5f * x * (1.0f + erff(x * 0.70710678118654752440f));
}
__device__ __forceinline__ float sigm_f(float x) {
    return 1.0f / (1.0f + expf(-x));
}
__device__ __forceinline__ unsigned short bf16_rne(float x) {
    unsigned int u = __float_as_uint(x);
    u += 0x7fffu + ((u >> 16) & 1u);
    return (unsigned short)(u >> 16);
}
__device__ __forceinline__ float bf16_to_f(unsigned short h) {
    return __uint_as_float(((unsigned int)h) << 16);
}

// ---------------- one-time weight split into bf16 hi/lo, K-major ----------------
__global__ __launch_bounds__(256) void prep_weights(
    const float* __restrict__ gw, const float* __restrict__ a1w, const float* __restrict__ a2w,
    unsigned short* __restrict__ wgh, unsigned short* __restrict__ wgl,
    unsigned short* __restrict__ a1h, unsigned short* __restrict__ a1l,
    unsigned short* __restrict__ a2h, unsigned short* __restrict__ a2l) {
    int i = blockIdx.x * 256 + threadIdx.x;
    float v; unsigned short* ph; unsigned short* pl; int idx;
    if (i < 147456) {
        int lev = i / 49152, r = i % 49152;
        int co = r / 384, k = r % 384, kp = k >> 7, ci = k & 127;
        v = gw[(((size_t)lev * C_ + co) * C_ + ci) * 3 + kp];
        ph = wgh; pl = wgl; idx = i;
    } else if (i < 147456 + 8192) {
        idx = i - 147456;
        v = a1w[idx];
        ph = a1h; pl = a1l;
    } else if (i < 147456 + 16384) {
        idx = i - 147456 - 8192;
        v = a2w[idx];
        ph = a2h; pl = a2l;
    } else return;
    unsigned short h = bf16_rne(v);
    unsigned short l = bf16_rne(v - bf16_to_f(h));
    ph[idx] = h; pl[idx] = l;
}

__device__ __forceinline__ float block_sum_256(float v, float* red) {
    #pragma unroll
    for (int off = 32; off > 0; off >>= 1) v += __shfl_down(v, off);
    const int wv = threadIdx.x >> 6, ln = threadIdx.x & 63;
    if (ln == 0) red[wv] = v;
    __syncthreads();
    return red[0] + red[1] + red[2] + red[3];
}

// ---------------- mean over L (level 0 feat), float4 ----------------
__global__ __launch_bounds__(256) void mean_kernel(const float* __restrict__ in,
                                                   float* __restrict__ feat_sum) {
    __shared__ float red[4];
    const int bc = blockIdx.x, t = threadIdx.x;
    const float4* p = (const float4*)(in + (size_t)bc * L_);
    float v = 0.f;
    #pragma unroll
    for (int it = 0; it < L_ / 1024; it++) {
        float4 x = p[t + 256 * it];
        v += x.x + x.y + x.z + x.w;
    }
    float tot = block_sum_256(v, red);
    if (t == 0) feat_sum[bc] = tot;
}

// ---------------- MLP layer: grid (N/16, samples); wave = 4 outputs, K split over 64 lanes ----
template <int K, int ACT>
__global__ __launch_bounds__(256) void mlp_layer(
    const float* __restrict__ X, const float* __restrict__ W,
    const float* __restrict__ bias, float* __restrict__ Y,
    int N, float xscale) {
    constexpr int PL = K / 64;
    const int w = threadIdx.x >> 6, ln = threadIdx.x & 63;
    const int s = blockIdx.y;
    const int o0 = blockIdx.x * 16 + w * 4;
    float xv[PL];
    const float* xr = X + (size_t)s * K + ln * PL;
    if constexpr (PL == 2) {
        float2 v = *(const float2*)xr;
        xv[0] = v.x * xscale; xv[1] = v.y * xscale;
    } else {
        #pragma unroll
        for (int i = 0; i < PL / 4; i++) {
            float4 v = *(const float4*)(xr + 4 * i);
            xv[4*i] = v.x * xscale; xv[4*i+1] = v.y * xscale;
            xv[4*i+2] = v.z * xscale; xv[4*i+3] = v.w * xscale;
        }
    }
    #pragma unroll
    for (int r = 0; r < 4; r++) {
        int o = o0 + r;
        if (o < N) {
            const float* wr = W + (size_t)o * K + ln * PL;
            float acc = 0.f;
            if constexpr (PL == 2) {
                float2 v = *(const float2*)wr;
                acc = v.x * xv[0] + v.y * xv[1];
            } else {
                #pragma unroll
                for (int i = 0; i < PL / 4; i++) {
                    float4 v = *(const float4*)(wr + 4 * i);
                    acc += v.x * xv[4*i] + v.y * xv[4*i+1] + v.z * xv[4*i+2] + v.w * xv[4*i+3];
                }
            }
            #pragma unroll
            for (int off = 32; off > 0; off >>= 1) acc += __shfl_xor(acc, off);
            if (ln == 0) {
                acc += bias[o];
                Y[(size_t)s * N + o] = ACT ? gelu_f(acc) : acc;
            }
        }
    }
}

// ---------------- MLP final layer: K=1024, 18 outputs split into lo/hi ----------------
__global__ __launch_bounds__(256) void mlp_l3(
    const float* __restrict__ X, const float* __restrict__ W, const float* __restrict__ bias,
    float* __restrict__ lo_out, float* __restrict__ hi_out) {
    constexpr int K = 2 * DIM_, PL = K / 64;
    const int w = threadIdx.x >> 6, ln = threadIdx.x & 63;
    const int s = blockIdx.y;
    const int o0 = blockIdx.x * 16 + w * 4;
    float xv[PL];
    const float* xr = X + (size_t)s * K + ln * PL;
    #pragma unroll
    for (int i = 0; i < PL / 4; i++) {
        float4 v = *(const float4*)(xr + 4 * i);
        xv[4*i] = v.x; xv[4*i+1] = v.y; xv[4*i+2] = v.z; xv[4*i+3] = v.w;
    }
    #pragma unroll
    for (int r = 0; r < 4; r++) {
        int o = o0 + r;
        if (o < 2 * FL_) {
            const float* wr = W + (size_t)o * K + ln * PL;
            float acc = 0.f;
            #pragma unroll
            for (int i = 0; i < PL / 4; i++) {
                float4 v = *(const float4*)(wr + 4 * i);
                acc += v.x * xv[4*i] + v.y * xv[4*i+1] + v.z * xv[4*i+2] + v.w * xv[4*i+3];
            }
            #pragma unroll
            for (int off = 32; off > 0; off >>= 1) acc += __shfl_xor(acc, off);
            if (ln == 0) {
                acc += bias[o];
                if (o < FL_) lo_out[s * FL_ + o] = acc;
                else         hi_out[s * FL_ + (o - FL_)] = acc;
            }
        }
    }
}

// ---------------- per-sample depthwise 9-tap conv (edge pad), float4, fused feat ----------------
__global__ __launch_bounds__(256) void dwconv_kernel(
    const float* __restrict__ in, const float* __restrict__ lo_f, const float* __restrict__ hi_f,
    float* __restrict__ out_lo, float* __restrict__ out_hi, float* __restrict__ feat_next) {
    __shared__ float s[1032];
    __shared__ float red[4];
    const int t = threadIdx.x;
    const int l0 = blockIdx.x * 1024;
    const int c = blockIdx.y, b = blockIdx.z;
    const size_t base = ((size_t)b * C_ + c) * L_;
    *(float4*)&s[4 + 4 * t] = *(const float4*)&in[base + l0 + 4 * t];
    if (t < 4) {
        int gl = l0 - 4 + t;
        s[t] = in[base + max(gl, 0)];
    } else if (t < 8) {
        int i = t - 4;
        s[1028 + i] = in[base + min(l0 + 1024 + i, L_ - 1)];
    }
    float lo[FL_], hi[FL_];
    #pragma unroll
    for (int k = 0; k < FL_; k++) { lo[k] = lo_f[b * FL_ + k]; hi[k] = hi_f[b * FL_ + k]; }
    __syncthreads();
    float oL[4] = {0, 0, 0, 0}, oH[4] = {0, 0, 0, 0};
    #pragma unroll
    for (int k = 0; k < FL_; k++) {
        #pragma unroll
        for (int r = 0; r < 4; r++) {
            float v = s[4 * t + r + k];
            oL[r] += lo[k] * v; oH[r] += hi[k] * v;
        }
    }
    *(float4*)&out_lo[base + l0 + 4 * t] = *(float4*)oL;
    *(float4*)&out_hi[base + l0 + 4 * t] = *(float4*)oH;
    if (feat_next) {
        float tot = block_sum_256(oL[0] + oL[1] + oL[2] + oL[3], red);
        if (t == 0) atomicAdd(&feat_next[b * C_ + c], tot);
    }
}

// ---------------- ortho + energy scalars ----------------
__global__ void ortho_kernel(const float* __restrict__ lo2, float* __restrict__ scal) {
    const int t = threadIdx.x;
    float smooth = 0.f, sabs2 = 0.f, amp = 0.f;
    if (t < B_) {
        const float* lo = lo2 + t * FL_;
        float ss = 0.f, sa = 0.f, sm = 0.f, prev = 0.f;
        #pragma unroll
        for (int k = 0; k < FL_; k++) {
            float v = lo[k];
            sm += fabsf(v - prev); prev = v;
            ss += v * v; sa += fabsf(v);
        }
        sm += fabsf(prev);
        float den = sqrtf(ss) + 1e-8f;
        float san = sa / den;
        sabs2 = san * san;
        amp = fabsf(ss / (den * den) - 1.0f);
        smooth = sm;
    }
    #pragma unroll
    for (int off = 32; off > 0; off >>= 1) {
        smooth += __shfl_down(smooth, off);
        sabs2  += __shfl_down(sabs2, off);
        amp    += __shfl_down(amp, off);
    }
    if (t == 0) {
        float lo_smooth = smooth / (float)(B_ * 10);
        float shift = 3.0f * (sabs2 / (float)B_) / 81.0f;
        scal[0] = 0.01f * (shift + amp / (float)B_) + 0.1f * lo_smooth;
        scal[1] = 0.0f;
    }
}

// ---------------- fused reconstruction via split-bf16 MFMA ----------------
// LDS = 46.6 KB -> 3 blocks/CU (12 waves) with __launch_bounds__(256,3).
#define LT   64
#define SX   136
#define SA   40
template <bool HAS_ATTN>
__global__ __launch_bounds__(256, 3) void recon_kernel(
    const float* __restrict__ cur_in, const float* __restrict__ det_in,
    float* __restrict__ det_out, float* __restrict__ cur_out,
    const unsigned short* __restrict__ wgh, const unsigned short* __restrict__ wgl,
    const float* __restrict__ gb,
    const unsigned short* __restrict__ a1h, const unsigned short* __restrict__ a1l,
    const float* __restrict__ b1,
    const unsigned short* __restrict__ a2h, const unsigned short* __restrict__ a2l,
    const float* __restrict__ b2) {
    __shared__ __attribute__((aligned(16))) unsigned short Xh[(LT + 2) * SX];
    __shared__ __attribute__((aligned(16))) unsigned short Xl[(LT + 2) * SX];
    __shared__ __attribute__((aligned(16))) unsigned short aTh[LT * SA];
    __shared__ __attribute__((aligned(16))) unsigned short aTl[LT * SA];

    const int t = threadIdx.x;
    const int b = blockIdx.y;
    const int l0 = blockIdx.x * LT;
    const float* curb = cur_in + (size_t)b * (C_ * L_);

    for (int u = t; u < 64 * (LT + 2); u += 256) {
        int cp = u / (LT + 2), li = u - cp * (LT + 2);
        int gl = l0 - 1 + li;
        float v0 = 0.f, v1 = 0.f;
        if (gl >= 0 && gl < L_) {
            v0 = curb[(size_t)(2 * cp) * L_ + gl];
            v1 = curb[(size_t)(2 * cp + 1) * L_ + gl];
        }
        unsigned short h0 = bf16_rne(v0), h1 = bf16_rne(v1);
        unsigned short e0 = bf16_rne(v0 - bf16_to_f(h0)), e1 = bf16_rne(v1 - bf16_to_f(h1));
        ((unsigned int*)Xh)[li * (SX / 2) + cp] = (unsigned int)h0 | ((unsigned int)h1 << 16);
        ((unsigned int*)Xl)[li * (SX / 2) + cp] = (unsigned int)e0 | ((unsigned int)e1 << 16);
    }

    const int w = t >> 6, ln = t & 15, q = (t >> 4) & 3;

    // det prefetch: issued after staging loads, completes under barrier + MFMA loop
    f32x4 dpv[2][4];
    #pragma unroll
    for (int tm = 0; tm < 2; tm++)
        #pragma unroll
        for (int tn = 0; tn < 4; tn++) {
            #pragma unroll
            for (int r = 0; r < 4; r++) {
                int co = 32 * w + 16 * tm + 4 * q + r;
                dpv[tm][tn][r] = det_in[((size_t)b * C_ + co) * L_ + l0 + 16 * tn + ln];
            }
        }
    __syncthreads();

    f32x4 acc[2][4];
    #pragma unroll
    for (int tm = 0; tm < 2; tm++)
        #pragma unroll
        for (int tn = 0; tn < 4; tn++) acc[tm][tn] = (f32x4){0.f, 0.f, 0.f, 0.f};

    #pragma unroll 2
    for (int kk = 0; kk < 12; kk++) {
        const int kp = kk >> 2, ci0 = (kk & 3) * 32;
        short8 ah[2], al[2];
        #pragma unroll
        for (int tm = 0; tm < 2; tm++) {
            int row = 32 * w + 16 * tm + ln;
            ah[tm] = *(const short8*)&wgh[row * 384 + kk * 32 + q * 8];
            al[tm] = *(const short8*)&wgl[row * 384 + kk * 32 + q * 8];
        }
        #pragma unroll
        for (int tn = 0; tn < 4; tn++) {
            int lrow = 16 * tn + ln + kp;
            const short8 bh = *(const short8*)&Xh[lrow * SX + ci0 + q * 8];
            const short8 bl = *(const short8*)&Xl[lrow * SX + ci0 + q * 8];
            #pragma unroll
            for (int tm = 0; tm < 2; tm++) {
                acc[tm][tn] = __builtin_amdgcn_mfma_f32_16x16x32_bf16(ah[tm], bh, acc[tm][tn], 0, 0, 0);
                acc[tm][tn] = __builtin_amdgcn_mfma_f32_16x16x32_bf16(ah[tm], bl, acc[tm][tn], 0, 0, 0);
                acc[tm][tn] = __builtin_amdgcn_mfma_f32_16x16x32_bf16(al[tm], bh, acc[tm][tn], 0, 0, 0);
            }
        }
    }

    if (HAS_ATTN) {
        f32x4 acc1[2];
        acc1[0] = (f32x4){0.f, 0.f, 0.f, 0.f};
        acc1[1] = (f32x4){0.f, 0.f, 0.f, 0.f};
        #pragma unroll
        for (int kc = 0; kc < 4; kc++) {
            int ci0 = kc * 32;
            int lrow = 16 * w + ln + 1;
            const short8 bh = *(const short8*)&Xh[lrow * SX + ci0 + q * 8];
            const short8 bl = *(const short8*)&Xl[lrow * SX + ci0 + q * 8];
            #pragma unroll
            for (int tm = 0; tm < 2; tm++) {
                int row = 16 * tm + ln;
                short8 fh = *(const short8*)&a1h[row * 128 + ci0 + q * 8];
                short8 fl = *(const short8*)&a1l[row * 128 + ci0 + q * 8];
                acc1[tm] = __builtin_amdgcn_mfma_f32_16x16x32_bf16(fh, bh, acc1[tm], 0, 0, 0);
                acc1[tm] = __builtin_amdgcn_mfma_f32_16x16x32_bf16(fh, bl, acc1[tm], 0, 0, 0);
                acc1[tm] = __builtin_amdgcn_mfma_f32_16x16x32_bf16(fl, bh, acc1[tm], 0, 0, 0);
            }
        }
        #pragma unroll
        for (int tm = 0; tm < 2; tm++) {
            #pragma unroll
            for (int r = 0; r < 4; r++) {
                int c32 = 16 * tm + 4 * q + r;
                int lcol = 16 * w + ln;
                float v = gelu_f(acc1[tm][r] + b1[c32]);
                unsigned short h = bf16_rne(v);
                aTh[lcol * SA + c32] = h;
                aTl[lcol * SA + c32] = bf16_rne(v - bf16_to_f(h));
            }
        }
        __syncthreads();
        f32x4 acc2[2][4];
        short8 fh2[2], fl2[2];
        #pragma unroll
        for (int tm = 0; tm < 2; tm++) {
            int row = 32 * w + 16 * tm + ln;
            fh2[tm] = *(const short8*)&a2h[row * 32 + q * 8];
            fl2[tm] = *(const short8*)&a2l[row * 32 + q * 8];
            #pragma unroll
            for (int tn = 0; tn < 4; tn++) acc2[tm][tn] = (f32x4){0.f, 0.f, 0.f, 0.f};
        }
        #pragma unroll
        for (int tn = 0; tn < 4; tn++) {
            int lrow = 16 * tn + ln;
            const short8 bh = *(const short8*)&aTh[lrow * SA + q * 8];
            const short8 bl = *(const short8*)&aTl[lrow * SA + q * 8];
            #pragma unroll
            for (int tm = 0; tm < 2; tm++) {
                acc2[tm][tn] = __builtin_amdgcn_mfma_f32_16x16x32_bf16(fh2[tm], bh, acc2[tm][tn], 0, 0, 0);
                acc2[tm][tn] = __builtin_amdgcn_mfma_f32_16x16x32_bf16(fh2[tm], bl, acc2[tm][tn], 0, 0, 0);
                acc2[tm][tn] = __builtin_amdgcn_mfma_f32_16x16x32_bf16(fl2[tm], bh, acc2[tm][tn], 0, 0, 0);
            }
        }
        #pragma unroll
        for (int tm = 0; tm < 2; tm++)
            #pragma unroll
            for (int tn = 0; tn < 4; tn++) {
                #pragma unroll
                for (int r = 0; r < 4; r++) {
                    int co = 32 * w + 16 * tm + 4 * q + r;
                    float at = sigm_f(acc2[tm][tn][r] + b2[co]);
                    float d = dpv[tm][tn][r];
                    d = d * at + d;
                    dpv[tm][tn][r] = d;
                    det_out[((size_t)b * C_ + co) * L_ + l0 + 16 * tn + ln] = d;
                }
            }
    }

    #pragma unroll
    for (int tm = 0; tm < 2; tm++)
        #pragma unroll
        for (int tn = 0; tn < 4; tn++) {
            #pragma unroll
            for (int r = 0; r < 4; r++) {
                int co = 32 * w + 16 * tm + 4 * q + r;
                int lrow = 16 * tn + ln + 1;
                float cur = bf16_to_f(Xh[lrow * SX + co]) + bf16_to_f(Xl[lrow * SX + co]);
                float g = sigm_f(acc[tm][tn][r] + gb[co]);
                cur_out[((size_t)b * C_ + co) * L_ + l0 + 16 * tn + ln] = cur + g * dpv[tm][tn][r];
            }
        }
}

static inline void run_mlp(const float* feat, const float* stat_w, const float* stat_b,
                           const float* wg1_w, const float* wg1_b,
                           const float* wg2_w, const float* wg2_b,
                           float* h1_g, float* h2_g, float* lo_out, float* hi_out,
                           hipStream_t stream) {
    mlp_layer<C_, 1><<<dim3(DIM_ / 16, B_), 256, 0, stream>>>(
        feat, stat_w, stat_b, h1_g, DIM_, 1.0f / (float)L_);
    mlp_layer<DIM_, 1><<<dim3(2 * DIM_ / 16, B_), 256, 0, stream>>>(
        h1_g, wg1_w, wg1_b, h2_g, 2 * DIM_, 1.0f);
    mlp_l3<<<dim3(2, B_), 256, 0, stream>>>(h2_g, wg2_w, wg2_b, lo_out, hi_out);
}

extern "C" void kernel_launch(void* const* d_in, const int* in_sizes, int n_in,
                              void* d_out, int out_size, void* d_ws, size_t ws_size,
                              hipStream_t stream) {
    (void)in_sizes; (void)n_in; (void)out_size; (void)ws_size;
    const float* x       = (const float*)d_in[0];
    const float* stat_w  = (const float*)d_in[1];
    const float* stat_b  = (const float*)d_in[2];
    const float* wg1_w   = (const float*)d_in[3];
    const float* wg1_b   = (const float*)d_in[4];
    const float* wg2_w   = (const float*)d_in[5];
    const float* wg2_b   = (const float*)d_in[6];
    const float* gates_w = (const float*)d_in[7];
    const float* gates_b = (const float*)d_in[8];
    const float* a1w     = (const float*)d_in[9];
    const float* a1b     = (const float*)d_in[10];
    const float* a2w     = (const float*)d_in[11];
    const float* a2b     = (const float*)d_in[12];

    float* out = (float*)d_out;
    float* yl  = out;
    float* yh0 = out + BCL;
    float* yh1 = out + 2 * BCL;
    float* yh2 = out + 3 * BCL;
    float* scal = out + 4 * BCL;
    float* lo_all = scal + 2;
    float* hi_all = lo_all + 3 * B_ * FL_;

    float* wsA   = (float*)d_ws;
    float* featA = wsA + BCL;
    float* featB = featA + B_ * C_;
    float* h1_g  = featB + B_ * C_;
    float* h2_g  = h1_g + B_ * DIM_;
    unsigned short* wgh = (unsigned short*)(h2_g + B_ * 2 * DIM_);
    unsigned short* wgl = wgh + 147456;
    unsigned short* a1h = wgl + 147456;
    unsigned short* a1l = a1h + 8192;
    unsigned short* a2h = a1l + 8192;
    unsigned short* a2l = a2h + 8192;

    prep_weights<<<dim3((147456 + 16384 + 255) / 256), 256, 0, stream>>>(
        gates_w, a1w, a2w, wgh, wgl, a1h, a1l, a2h, a2l);

    const dim3 cgrid(L_ / 1024, C_, B_);
    const dim3 rgrid(L_ / LT, B_);

    // ---- analysis level 0 ----
    mean_kernel<<<dim3(B_ * C_), 256, 0, stream>>>(x, featA);
    run_mlp(featA, stat_w, stat_b, wg1_w, wg1_b, wg2_w, wg2_b, h1_g, h2_g,
            lo_all, hi_all, stream);
    hipMemsetAsync(featB, 0, B_ * C_ * sizeof(float), stream);
    dwconv_kernel<<<cgrid, 256, 0, stream>>>(x, lo_all, hi_all, wsA, yh0, featB);
    // ---- analysis level 1 ----
    run_mlp(featB, stat_w, stat_b, wg1_w, wg1_b, wg2_w, wg2_b, h1_g, h2_g,
            lo_all + B_ * FL_, hi_all + B_ * FL_, stream);
    hipMemsetAsync(featA, 0, B_ * C_ * sizeof(float), stream);
    dwconv_kernel<<<cgrid, 256, 0, stream>>>(wsA, lo_all + B_ * FL_, hi_all + B_ * FL_, yl, yh1, featA);
    // ---- analysis level 2 ----
    run_mlp(featA, stat_w, stat_b, wg1_w, wg1_b, wg2_w, wg2_b, h1_g, h2_g,
            lo_all + 2 * B_ * FL_, hi_all + 2 * B_ * FL_, stream);
    dwconv_kernel<<<cgrid, 256, 0, stream>>>(yl, lo_all + 2 * B_ * FL_, hi_all + 2 * B_ * FL_,
                                             wsA, yh2, nullptr);
    // ---- scalars ----
    ortho_kernel<<<dim3(1), 64, 0, stream>>>(lo_all + 2 * B_ * FL_, scal);
    // ---- reconstruction: i=2 (no attn), i=1, i=0 ----
    recon_kernel<false><<<rgrid, 256, 0, stream>>>(wsA, yh2, nullptr, yl,
        wgh + 2 * 49152, wgl + 2 * 49152, gates_b + 2 * C_,
        nullptr, nullptr, nullptr, nullptr, nullptr, nullptr);
    recon_kernel<true><<<rgrid, 256, 0, stream>>>(yl, yh1, yh1, wsA,
        wgh + 1 * 49152, wgl + 1 * 49152, gates_b + 1 * C_,
        a1h + 4096, a1l + 4096, a1b + 32,
        a2h + 4096, a2l + 4096, a2b + C_);
    recon_kernel<true><<<rgrid, 256, 0, stream>>>(wsA, yh0, yh0, yl,
        wgh, wgl, gates_b,
        a1h, a1l, a1b,
        a2h, a2l, a2b);
}

// Round 5
// 745.439 us; speedup vs baseline: 1.5594x; 1.0208x over previous
//
#include <hip/hip_runtime.h>

#define B_   32
#define C_   128
#define L_   4096
#define FL_  9
#define DIM_ 512
#define BCL  ((size_t)B_ * C_ * L_)

typedef __attribute__((ext_vector_type(8))) short short8;
typedef __attribute__((ext_vector_type(4))) float f32x4;

__device__ __forceinline__ float gelu_f(float x) {
    return 0.5f * x * (1.0f + erff(x * 0.70710678118654752440f));
}
__device__ __forceinline__ unsigned short bf16_rne(float x) {
    unsigned int u = __float_as_uint(x);
    u += 0x7fffu + ((u >> 16) & 1u);
    return (unsigned short)(u >> 16);
}
__device__ __forceinline__ float bf16_to_f(unsigned short h) {
    return __uint_as_float(((unsigned int)h) << 16);
}
// packed bf16 convert: low16 = bf16(a), high16 = bf16(b) (hardware)
__device__ __forceinline__ unsigned int cvt_pk_bf16(float a, float b) {
    unsigned int r;
    asm("v_cvt_pk_bf16_f32 %0, %1, %2" : "=v"(r) : "v"(a), "v"(b));
    return r;
}
__device__ __forceinline__ float lo16f(unsigned int u) { return __uint_as_float(u << 16); }
__device__ __forceinline__ float hi16f(unsigned int u) { return __uint_as_float(u & 0xffff0000u); }
// fast sigmoid: v_exp + v_rcp (~4 VALU), |err| ~1e-5
__device__ __forceinline__ float fast_sigm(float x) {
    float e;
    asm("v_exp_f32 %0, %1" : "=v"(e) : "v"(x * -1.44269504088896341f));
    float r;
    asm("v_rcp_f32 %0, %1" : "=v"(r) : "v"(1.0f + e));
    return r;
}
__device__ __forceinline__ float sigm_f(float x) {
    return 1.0f / (1.0f + expf(-x));
}

// ---------------- one-time weight split into bf16 hi/lo, K-major ----------------
__global__ __launch_bounds__(256) void prep_weights(
    const float* __restrict__ gw, const float* __restrict__ a1w, const float* __restrict__ a2w,
    unsigned short* __restrict__ wgh, unsigned short* __restrict__ wgl,
    unsigned short* __restrict__ a1h, unsigned short* __restrict__ a1l,
    unsigned short* __restrict__ a2h, unsigned short* __restrict__ a2l) {
    int i = blockIdx.x * 256 + threadIdx.x;
    float v; unsigned short* ph; unsigned short* pl; int idx;
    if (i < 147456) {
        int lev = i / 49152, r = i % 49152;
        int co = r / 384, k = r % 384, kp = k >> 7, ci = k & 127;
        v = gw[(((size_t)lev * C_ + co) * C_ + ci) * 3 + kp];
        ph = wgh; pl = wgl; idx = i;
    } else if (i < 147456 + 8192) {
        idx = i - 147456;
        v = a1w[idx];
        ph = a1h; pl = a1l;
    } else if (i < 147456 + 16384) {
        idx = i - 147456 - 8192;
        v = a2w[idx];
        ph = a2h; pl = a2l;
    } else return;
    unsigned short h = bf16_rne(v);
    unsigned short l = bf16_rne(v - bf16_to_f(h));
    ph[idx] = h; pl[idx] = l;
}

__device__ __forceinline__ float block_sum_256(float v, float* red) {
    #pragma unroll
    for (int off = 32; off > 0; off >>= 1) v += __shfl_down(v, off);
    const int wv = threadIdx.x >> 6, ln = threadIdx.x & 63;
    if (ln == 0) red[wv] = v;
    __syncthreads();
    return red[0] + red[1] + red[2] + red[3];
}

// ---------------- mean over L (level 0 feat), float4 ----------------
__global__ __launch_bounds__(256) void mean_kernel(const float* __restrict__ in,
                                                   float* __restrict__ feat_sum) {
    __shared__ float red[4];
    const int bc = blockIdx.x, t = threadIdx.x;
    const float4* p = (const float4*)(in + (size_t)bc * L_);
    float v = 0.f;
    #pragma unroll
    for (int it = 0; it < L_ / 1024; it++) {
        float4 x = p[t + 256 * it];
        v += x.x + x.y + x.z + x.w;
    }
    float tot = block_sum_256(v, red);
    if (t == 0) feat_sum[bc] = tot;
}

// ---------------- MLP layer: grid (N/16, samples); wave = 4 outputs, K split over 64 lanes ----
template <int K, int ACT>
__global__ __launch_bounds__(256) void mlp_layer(
    const float* __restrict__ X, const float* __restrict__ W,
    const float* __restrict__ bias, float* __restrict__ Y,
    int N, float xscale) {
    constexpr int PL = K / 64;
    const int w = threadIdx.x >> 6, ln = threadIdx.x & 63;
    const int s = blockIdx.y;
    const int o0 = blockIdx.x * 16 + w * 4;
    float xv[PL];
    const float* xr = X + (size_t)s * K + ln * PL;
    if constexpr (PL == 2) {
        float2 v = *(const float2*)xr;
        xv[0] = v.x * xscale; xv[1] = v.y * xscale;
    } else {
        #pragma unroll
        for (int i = 0; i < PL / 4; i++) {
            float4 v = *(const float4*)(xr + 4 * i);
            xv[4*i] = v.x * xscale; xv[4*i+1] = v.y * xscale;
            xv[4*i+2] = v.z * xscale; xv[4*i+3] = v.w * xscale;
        }
    }
    #pragma unroll
    for (int r = 0; r < 4; r++) {
        int o = o0 + r;
        if (o < N) {
            const float* wr = W + (size_t)o * K + ln * PL;
            float acc = 0.f;
            if constexpr (PL == 2) {
                float2 v = *(const float2*)wr;
                acc = v.x * xv[0] + v.y * xv[1];
            } else {
                #pragma unroll
                for (int i = 0; i < PL / 4; i++) {
                    float4 v = *(const float4*)(wr + 4 * i);
                    acc += v.x * xv[4*i] + v.y * xv[4*i+1] + v.z * xv[4*i+2] + v.w * xv[4*i+3];
                }
            }
            #pragma unroll
            for (int off = 32; off > 0; off >>= 1) acc += __shfl_xor(acc, off);
            if (ln == 0) {
                acc += bias[o];
                Y[(size_t)s * N + o] = ACT ? gelu_f(acc) : acc;
            }
        }
    }
}

// ---------------- MLP final layer: K=1024, 18 outputs split into lo/hi ----------------
__global__ __launch_bounds__(256) void mlp_l3(
    const float* __restrict__ X, const float* __restrict__ W, const float* __restrict__ bias,
    float* __restrict__ lo_out, float* __restrict__ hi_out) {
    constexpr int K = 2 * DIM_, PL = K / 64;
    const int w = threadIdx.x >> 6, ln = threadIdx.x & 63;
    const int s = blockIdx.y;
    const int o0 = blockIdx.x * 16 + w * 4;
    float xv[PL];
    const float* xr = X + (size_t)s * K + ln * PL;
    #pragma unroll
    for (int i = 0; i < PL / 4; i++) {
        float4 v = *(const float4*)(xr + 4 * i);
        xv[4*i] = v.x; xv[4*i+1] = v.y; xv[4*i+2] = v.z; xv[4*i+3] = v.w;
    }
    #pragma unroll
    for (int r = 0; r < 4; r++) {
        int o = o0 + r;
        if (o < 2 * FL_) {
            const float* wr = W + (size_t)o * K + ln * PL;
            float acc = 0.f;
            #pragma unroll
            for (int i = 0; i < PL / 4; i++) {
                float4 v = *(const float4*)(wr + 4 * i);
                acc += v.x * xv[4*i] + v.y * xv[4*i+1] + v.z * xv[4*i+2] + v.w * xv[4*i+3];
            }
            #pragma unroll
            for (int off = 32; off > 0; off >>= 1) acc += __shfl_xor(acc, off);
            if (ln == 0) {
                acc += bias[o];
                if (o < FL_) lo_out[s * FL_ + o] = acc;
                else         hi_out[s * FL_ + (o - FL_)] = acc;
            }
        }
    }
}

// ---------------- per-sample depthwise 9-tap conv (edge pad), float4, fused feat ----------------
__global__ __launch_bounds__(256) void dwconv_kernel(
    const float* __restrict__ in, const float* __restrict__ lo_f, const float* __restrict__ hi_f,
    float* __restrict__ out_lo, float* __restrict__ out_hi, float* __restrict__ feat_next) {
    __shared__ float s[1032];
    __shared__ float red[4];
    const int t = threadIdx.x;
    const int l0 = blockIdx.x * 1024;
    const int c = blockIdx.y, b = blockIdx.z;
    const size_t base = ((size_t)b * C_ + c) * L_;
    *(float4*)&s[4 + 4 * t] = *(const float4*)&in[base + l0 + 4 * t];
    if (t < 4) {
        int gl = l0 - 4 + t;
        s[t] = in[base + max(gl, 0)];
    } else if (t < 8) {
        int i = t - 4;
        s[1028 + i] = in[base + min(l0 + 1024 + i, L_ - 1)];
    }
    float lo[FL_], hi[FL_];
    #pragma unroll
    for (int k = 0; k < FL_; k++) { lo[k] = lo_f[b * FL_ + k]; hi[k] = hi_f[b * FL_ + k]; }
    __syncthreads();
    float oL[4] = {0, 0, 0, 0}, oH[4] = {0, 0, 0, 0};
    #pragma unroll
    for (int k = 0; k < FL_; k++) {
        #pragma unroll
        for (int r = 0; r < 4; r++) {
            float v = s[4 * t + r + k];
            oL[r] += lo[k] * v; oH[r] += hi[k] * v;
        }
    }
    *(float4*)&out_lo[base + l0 + 4 * t] = *(float4*)oL;
    *(float4*)&out_hi[base + l0 + 4 * t] = *(float4*)oH;
    if (feat_next) {
        float tot = block_sum_256(oL[0] + oL[1] + oL[2] + oL[3], red);
        if (t == 0) atomicAdd(&feat_next[b * C_ + c], tot);
    }
}

// ---------------- ortho + energy scalars ----------------
__global__ void ortho_kernel(const float* __restrict__ lo2, float* __restrict__ scal) {
    const int t = threadIdx.x;
    float smooth = 0.f, sabs2 = 0.f, amp = 0.f;
    if (t < B_) {
        const float* lo = lo2 + t * FL_;
        float ss = 0.f, sa = 0.f, sm = 0.f, prev = 0.f;
        #pragma unroll
        for (int k = 0; k < FL_; k++) {
            float v = lo[k];
            sm += fabsf(v - prev); prev = v;
            ss += v * v; sa += fabsf(v);
        }
        sm += fabsf(prev);
        float den = sqrtf(ss) + 1e-8f;
        float san = sa / den;
        sabs2 = san * san;
        amp = fabsf(ss / (den * den) - 1.0f);
        smooth = sm;
    }
    #pragma unroll
    for (int off = 32; off > 0; off >>= 1) {
        smooth += __shfl_down(smooth, off);
        sabs2  += __shfl_down(sabs2, off);
        amp    += __shfl_down(amp, off);
    }
    if (t == 0) {
        float lo_smooth = smooth / (float)(B_ * 10);
        float shift = 3.0f * (sabs2 / (float)B_) / 81.0f;
        scal[0] = 0.01f * (shift + amp / (float)B_) + 0.1f * lo_smooth;
        scal[1] = 0.0f;
    }
}

// ---------------- fused reconstruction via split-bf16 MFMA ----------------
// LDS = 46.6 KB -> 3 blocks/CU (12 waves). VALU-lean: cvt_pk staging, fast sigmoid,
// packed u32 epilogue reads.
#define LT   64
#define SX   136
#define SA   40
template <bool HAS_ATTN>
__global__ __launch_bounds__(256, 3) void recon_kernel(
    const float* __restrict__ cur_in, const float* __restrict__ det_in,
    float* __restrict__ det_out, float* __restrict__ cur_out,
    const unsigned short* __restrict__ wgh, const unsigned short* __restrict__ wgl,
    const float* __restrict__ gb,
    const unsigned short* __restrict__ a1h, const unsigned short* __restrict__ a1l,
    const float* __restrict__ b1,
    const unsigned short* __restrict__ a2h, const unsigned short* __restrict__ a2l,
    const float* __restrict__ b2) {
    __shared__ __attribute__((aligned(16))) unsigned short Xh[(LT + 2) * SX];
    __shared__ __attribute__((aligned(16))) unsigned short Xl[(LT + 2) * SX];
    __shared__ __attribute__((aligned(16))) unsigned short aTh[LT * SA];
    __shared__ __attribute__((aligned(16))) unsigned short aTl[LT * SA];
    unsigned int* Xh32 = (unsigned int*)Xh;
    unsigned int* Xl32 = (unsigned int*)Xl;
    unsigned int* aTh32 = (unsigned int*)aTh;
    unsigned int* aTl32 = (unsigned int*)aTl;

    const int t = threadIdx.x;
    const int b = blockIdx.y;
    const int l0 = blockIdx.x * LT;
    const float* curb = cur_in + (size_t)b * (C_ * L_);

    // ---- staging: vectorized float4-pair loads + cvt_pk bf16 split ----
    // core rows li=1..64 (gl = l0..l0+63, always in-bounds)
    #pragma unroll
    for (int it = 0; it < 4; it++) {
        int v = t + 256 * it;
        int cp = v >> 4, ch = v & 15;
        const float* p0 = curb + (size_t)(2 * cp) * L_ + (l0 + 4 * ch);
        float4 A  = *(const float4*)p0;
        float4 Bv = *(const float4*)(p0 + L_);
        int li0 = 1 + 4 * ch;
        #pragma unroll
        for (int j = 0; j < 4; j++) {
            float a = ((const float*)&A)[j], c = ((const float*)&Bv)[j];
            unsigned int uh = cvt_pk_bf16(a, c);
            unsigned int ul = cvt_pk_bf16(a - lo16f(uh), c - hi16f(uh));
            Xh32[(li0 + j) * (SX / 2) + cp] = uh;
            Xl32[(li0 + j) * (SX / 2) + cp] = ul;
        }
    }
    // halo rows li=0 and li=65
    if (t < 128) {
        int cp = t >> 1, side = t & 1;
        int li = side ? (LT + 1) : 0;
        int gl = l0 - 1 + li;
        float v0 = 0.f, v1 = 0.f;
        if (gl >= 0 && gl < L_) {
            v0 = curb[(size_t)(2 * cp) * L_ + gl];
            v1 = curb[(size_t)(2 * cp + 1) * L_ + gl];
        }
        unsigned int uh = cvt_pk_bf16(v0, v1);
        unsigned int ul = cvt_pk_bf16(v0 - lo16f(uh), v1 - hi16f(uh));
        Xh32[li * (SX / 2) + cp] = uh;
        Xl32[li * (SX / 2) + cp] = ul;
    }
    __syncthreads();

    const int w = t >> 6, ln = t & 15, q = (t >> 4) & 3;

    // det prefetch: issue now, latency hides under the 12-iteration MFMA loop
    f32x4 dpv[2][4];
    #pragma unroll
    for (int tm = 0; tm < 2; tm++)
        #pragma unroll
        for (int tn = 0; tn < 4; tn++) {
            #pragma unroll
            for (int r = 0; r < 4; r++) {
                int co = 32 * w + 16 * tm + 4 * q + r;
                dpv[tm][tn][r] = det_in[((size_t)b * C_ + co) * L_ + l0 + 16 * tn + ln];
            }
        }

    f32x4 acc[2][4];
    #pragma unroll
    for (int tm = 0; tm < 2; tm++)
        #pragma unroll
        for (int tn = 0; tn < 4; tn++) acc[tm][tn] = (f32x4){0.f, 0.f, 0.f, 0.f};

    #pragma unroll 2
    for (int kk = 0; kk < 12; kk++) {
        const int kp = kk >> 2, ci0 = (kk & 3) * 32;
        short8 ah[2], al[2];
        #pragma unroll
        for (int tm = 0; tm < 2; tm++) {
            int row = 32 * w + 16 * tm + ln;
            ah[tm] = *(const short8*)&wgh[row * 384 + kk * 32 + q * 8];
            al[tm] = *(const short8*)&wgl[row * 384 + kk * 32 + q * 8];
        }
        #pragma unroll
        for (int tn = 0; tn < 4; tn++) {
            int lrow = 16 * tn + ln + kp;
            const short8 bh = *(const short8*)&Xh[lrow * SX + ci0 + q * 8];
            const short8 bl = *(const short8*)&Xl[lrow * SX + ci0 + q * 8];
            #pragma unroll
            for (int tm = 0; tm < 2; tm++) {
                acc[tm][tn] = __builtin_amdgcn_mfma_f32_16x16x32_bf16(ah[tm], bh, acc[tm][tn], 0, 0, 0);
                acc[tm][tn] = __builtin_amdgcn_mfma_f32_16x16x32_bf16(ah[tm], bl, acc[tm][tn], 0, 0, 0);
                acc[tm][tn] = __builtin_amdgcn_mfma_f32_16x16x32_bf16(al[tm], bh, acc[tm][tn], 0, 0, 0);
            }
        }
    }

    if (HAS_ATTN) {
        f32x4 acc1[2];
        acc1[0] = (f32x4){0.f, 0.f, 0.f, 0.f};
        acc1[1] = (f32x4){0.f, 0.f, 0.f, 0.f};
        #pragma unroll
        for (int kc = 0; kc < 4; kc++) {
            int ci0 = kc * 32;
            int lrow = 16 * w + ln + 1;
            const short8 bh = *(const short8*)&Xh[lrow * SX + ci0 + q * 8];
            const short8 bl = *(const short8*)&Xl[lrow * SX + ci0 + q * 8];
            #pragma unroll
            for (int tm = 0; tm < 2; tm++) {
                int row = 16 * tm + ln;
                short8 fh = *(const short8*)&a1h[row * 128 + ci0 + q * 8];
                short8 fl = *(const short8*)&a1l[row * 128 + ci0 + q * 8];
                acc1[tm] = __builtin_amdgcn_mfma_f32_16x16x32_bf16(fh, bh, acc1[tm], 0, 0, 0);
                acc1[tm] = __builtin_amdgcn_mfma_f32_16x16x32_bf16(fh, bl, acc1[tm], 0, 0, 0);
                acc1[tm] = __builtin_amdgcn_mfma_f32_16x16x32_bf16(fl, bh, acc1[tm], 0, 0, 0);
            }
        }
        #pragma unroll
        for (int tm = 0; tm < 2; tm++) {
            int cb = 16 * tm + 4 * q;
            int lcol = 16 * w + ln;
            float v0 = gelu_f(acc1[tm][0] + b1[cb + 0]);
            float v1 = gelu_f(acc1[tm][1] + b1[cb + 1]);
            float v2 = gelu_f(acc1[tm][2] + b1[cb + 2]);
            float v3 = gelu_f(acc1[tm][3] + b1[cb + 3]);
            unsigned int h01 = cvt_pk_bf16(v0, v1);
            unsigned int l01 = cvt_pk_bf16(v0 - lo16f(h01), v1 - hi16f(h01));
            unsigned int h23 = cvt_pk_bf16(v2, v3);
            unsigned int l23 = cvt_pk_bf16(v2 - lo16f(h23), v3 - hi16f(h23));
            int ci = lcol * (SA / 2) + (cb >> 1);
            aTh32[ci] = h01; aTh32[ci + 1] = h23;
            aTl32[ci] = l01; aTl32[ci + 1] = l23;
        }
        __syncthreads();
        f32x4 acc2[2][4];
        short8 fh2[2], fl2[2];
        #pragma unroll
        for (int tm = 0; tm < 2; tm++) {
            int row = 32 * w + 16 * tm + ln;
            fh2[tm] = *(const short8*)&a2h[row * 32 + q * 8];
            fl2[tm] = *(const short8*)&a2l[row * 32 + q * 8];
            #pragma unroll
            for (int tn = 0; tn < 4; tn++) acc2[tm][tn] = (f32x4){0.f, 0.f, 0.f, 0.f};
        }
        #pragma unroll
        for (int tn = 0; tn < 4; tn++) {
            int lrow = 16 * tn + ln;
            const short8 bh = *(const short8*)&aTh[lrow * SA + q * 8];
            const short8 bl = *(const short8*)&aTl[lrow * SA + q * 8];
            #pragma unroll
            for (int tm = 0; tm < 2; tm++) {
                acc2[tm][tn] = __builtin_amdgcn_mfma_f32_16x16x32_bf16(fh2[tm], bh, acc2[tm][tn], 0, 0, 0);
                acc2[tm][tn] = __builtin_amdgcn_mfma_f32_16x16x32_bf16(fh2[tm], bl, acc2[tm][tn], 0, 0, 0);
                acc2[tm][tn] = __builtin_amdgcn_mfma_f32_16x16x32_bf16(fl2[tm], bh, acc2[tm][tn], 0, 0, 0);
            }
        }
        #pragma unroll
        for (int tm = 0; tm < 2; tm++)
            #pragma unroll
            for (int tn = 0; tn < 4; tn++) {
                #pragma unroll
                for (int r = 0; r < 4; r++) {
                    int co = 32 * w + 16 * tm + 4 * q + r;
                    float at = fast_sigm(acc2[tm][tn][r] + b2[co]);
                    float d = dpv[tm][tn][r];
                    d = d * at + d;
                    dpv[tm][tn][r] = d;
                    det_out[((size_t)b * C_ + co) * L_ + l0 + 16 * tn + ln] = d;
                }
            }
    }

    #pragma unroll
    for (int tm = 0; tm < 2; tm++)
        #pragma unroll
        for (int tn = 0; tn < 4; tn++) {
            int lrow = 16 * tn + ln + 1;
            int cbase = 32 * w + 16 * tm + 4 * q;
            int ci = lrow * (SX / 2) + (cbase >> 1);
            unsigned int uh0 = Xh32[ci],     ul0 = Xl32[ci];
            unsigned int uh1 = Xh32[ci + 1], ul1 = Xl32[ci + 1];
            float cf[4];
            cf[0] = lo16f(uh0) + lo16f(ul0);
            cf[1] = hi16f(uh0) + hi16f(ul0);
            cf[2] = lo16f(uh1) + lo16f(ul1);
            cf[3] = hi16f(uh1) + hi16f(ul1);
            #pragma unroll
            for (int r = 0; r < 4; r++) {
                int co = cbase + r;
                float g = fast_sigm(acc[tm][tn][r] + gb[co]);
                cur_out[((size_t)b * C_ + co) * L_ + l0 + 16 * tn + ln] = cf[r] + g * dpv[tm][tn][r];
            }
        }
}

static inline void run_mlp(const float* feat, const float* stat_w, const float* stat_b,
                           const float* wg1_w, const float* wg1_b,
                           const float* wg2_w, const float* wg2_b,
                           float* h1_g, float* h2_g, float* lo_out, float* hi_out,
                           hipStream_t stream) {
    mlp_layer<C_, 1><<<dim3(DIM_ / 16, B_), 256, 0, stream>>>(
        feat, stat_w, stat_b, h1_g, DIM_, 1.0f / (float)L_);
    mlp_layer<DIM_, 1><<<dim3(2 * DIM_ / 16, B_), 256, 0, stream>>>(
        h1_g, wg1_w, wg1_b, h2_g, 2 * DIM_, 1.0f);
    mlp_l3<<<dim3(2, B_), 256, 0, stream>>>(h2_g, wg2_w, wg2_b, lo_out, hi_out);
}

extern "C" void kernel_launch(void* const* d_in, const int* in_sizes, int n_in,
                              void* d_out, int out_size, void* d_ws, size_t ws_size,
                              hipStream_t stream) {
    (void)in_sizes; (void)n_in; (void)out_size; (void)ws_size;
    const float* x       = (const float*)d_in[0];
    const float* stat_w  = (const float*)d_in[1];
    const float* stat_b  = (const float*)d_in[2];
    const float* wg1_w   = (const float*)d_in[3];
    const float* wg1_b   = (const float*)d_in[4];
    const float* wg2_w   = (const float*)d_in[5];
    const float* wg2_b   = (const float*)d_in[6];
    const float* gates_w = (const float*)d_in[7];
    const float* gates_b = (const float*)d_in[8];
    const float* a1w     = (const float*)d_in[9];
    const float* a1b     = (const float*)d_in[10];
    const float* a2w     = (const float*)d_in[11];
    const float* a2b     = (const float*)d_in[12];

    float* out = (float*)d_out;
    float* yl  = out;
    float* yh0 = out + BCL;
    float* yh1 = out + 2 * BCL;
    float* yh2 = out + 3 * BCL;
    float* scal = out + 4 * BCL;
    float* lo_all = scal + 2;
    float* hi_all = lo_all + 3 * B_ * FL_;

    float* wsA   = (float*)d_ws;
    float* featA = wsA + BCL;
    float* featB = featA + B_ * C_;
    float* h1_g  = featB + B_ * C_;
    float* h2_g  = h1_g + B_ * DIM_;
    unsigned short* wgh = (unsigned short*)(h2_g + B_ * 2 * DIM_);
    unsigned short* wgl = wgh + 147456;
    unsigned short* a1h = wgl + 147456;
    unsigned short* a1l = a1h + 8192;
    unsigned short* a2h = a1l + 8192;
    unsigned short* a2l = a2h + 8192;

    prep_weights<<<dim3((147456 + 16384 + 255) / 256), 256, 0, stream>>>(
        gates_w, a1w, a2w, wgh, wgl, a1h, a1l, a2h, a2l);

    const dim3 cgrid(L_ / 1024, C_, B_);
    const dim3 rgrid(L_ / LT, B_);

    // ---- analysis level 0 ----
    mean_kernel<<<dim3(B_ * C_), 256, 0, stream>>>(x, featA);
    run_mlp(featA, stat_w, stat_b, wg1_w, wg1_b, wg2_w, wg2_b, h1_g, h2_g,
            lo_all, hi_all, stream);
    hipMemsetAsync(featB, 0, B_ * C_ * sizeof(float), stream);
    dwconv_kernel<<<cgrid, 256, 0, stream>>>(x, lo_all, hi_all, wsA, yh0, featB);
    // ---- analysis level 1 ----
    run_mlp(featB, stat_w, stat_b, wg1_w, wg1_b, wg2_w, wg2_b, h1_g, h2_g,
            lo_all + B_ * FL_, hi_all + B_ * FL_, stream);
    hipMemsetAsync(featA, 0, B_ * C_ * sizeof(float), stream);
    dwconv_kernel<<<cgrid, 256, 0, stream>>>(wsA, lo_all + B_ * FL_, hi_all + B_ * FL_, yl, yh1, featA);
    // ---- analysis level 2 ----
    run_mlp(featA, stat_w, stat_b, wg1_w, wg1_b, wg2_w, wg2_b, h1_g, h2_g,
            lo_all + 2 * B_ * FL_, hi_all + 2 * B_ * FL_, stream);
    dwconv_kernel<<<cgrid, 256, 0, stream>>>(yl, lo_all + 2 * B_ * FL_, hi_all + 2 * B_ * FL_,
                                             wsA, yh2, nullptr);
    // ---- scalars ----
    ortho_kernel<<<dim3(1), 64, 0, stream>>>(lo_all + 2 * B_ * FL_, scal);
    // ---- reconstruction: i=2 (no attn), i=1, i=0 ----
    recon_kernel<false><<<rgrid, 256, 0, stream>>>(wsA, yh2, nullptr, yl,
        wgh + 2 * 49152, wgl + 2 * 49152, gates_b + 2 * C_,
        nullptr, nullptr, nullptr, nullptr, nullptr, nullptr);
    recon_kernel<true><<<rgrid, 256, 0, stream>>>(yl, yh1, yh1, wsA,
        wgh + 1 * 49152, wgl + 1 * 49152, gates_b + 1 * C_,
        a1h + 4096, a1l + 4096, a1b + 32,
        a2h + 4096, a2l + 4096, a2b + C_);
    recon_kernel<true><<<rgrid, 256, 0, stream>>>(wsA, yh0, yh0, yl,
        wgh, wgl, gates_b,
        a1h, a1l, a1b,
        a2h, a2l, a2b);
}